// Round 2
// baseline (83814.252 us; speedup 1.0000x reference)
//
#include <hip/hip_runtime.h>
#include <hip/hip_fp16.h>

// Speller (LAS decoder): 3x LSTMCell + dot attention + CDN head.
// B=128 S=600 T=200 ENC=512 P=128 E=256 H=512 V=31.
// Round 2: persistent cooperative kernel. 3 launches total:
//   init_kernel, kv_kernel, persist_kernel (200-step loop, 4 grid barriers/step).
// Grid barriers: flag-array arrive + block0 master poll + go generation counter,
// all device-scope atomics, monotone iteration counter (ws poisoned -> zeroed in init).

#define Bc 128
#define Sc 600
#define Tc 200
#define ENCc 512
#define Pc 128
#define Ec 256
#define Hc 512
#define Vc 31
#define BHc (Bc * Hc)

__device__ __forceinline__ float sigmoidf_(float x) { return 1.f / (1.f + expf(-x)); }

// ---------------- init: h/c state, xin0 = [emb(SOS) | 0], zero barrier flags ----------------
__global__ __launch_bounds__(256) void init_kernel(
    const float* __restrict__ h0, const float* __restrict__ c0,
    const float* __restrict__ emb,
    float* __restrict__ hbuf, float* __restrict__ cst,
    float* __restrict__ xin0, unsigned* __restrict__ bar)
{
  const int i = blockIdx.x * 256 + threadIdx.x;
  if (i < 3 * BHc) { hbuf[i] = h0[i]; cst[i] = c0[i]; }
  if (i < Bc * 384) {
    const int k = i % 384;
    xin0[i] = (k < 256) ? emb[256 + k] : 0.f;   // SOS token = 1
  }
  if (i < 257) bar[i] = 0u;
}

// ---------------- key/value projection (once) ----------------
__global__ __launch_bounds__(256) void kv_kernel(
    const float* __restrict__ x,
    const float* __restrict__ KW_w, const float* __restrict__ KW_b,
    const float* __restrict__ VW_w, const float* __restrict__ VW_b,
    __half* __restrict__ key16, __half* __restrict__ val16)
{
  const int r0 = blockIdx.x * 32;
  const int tid = threadIdx.x;
  const bool isv = tid >= 128;
  const int p = tid & 127;
  const float* __restrict__ W = isv ? VW_w : KW_w;
  float acc[32];
#pragma unroll
  for (int r = 0; r < 32; ++r) acc[r] = 0.f;
  __shared__ float xs[32][64];
  for (int c = 0; c < 8; ++c) {
    const int k0 = c * 64;
    __syncthreads();
#pragma unroll
    for (int i = 0; i < 2; ++i) {
      const int e = i * 256 + tid;
      const int row = e >> 4, c4 = e & 15;
      *(float4*)(&xs[row][c4 * 4]) =
          *(const float4*)(x + (size_t)(r0 + row) * ENCc + k0 + c4 * 4);
    }
    __syncthreads();
    const float* wr = W + (size_t)p * ENCc + k0;
#pragma unroll
    for (int kk = 0; kk < 16; ++kk) {
      const float4 w4 = *(const float4*)(wr + kk * 4);
#pragma unroll
      for (int r = 0; r < 32; ++r) {
        const float4 xv = *(const float4*)(&xs[r][kk * 4]);
        acc[r] += w4.x * xv.x + w4.y * xv.y + w4.z * xv.z + w4.w * xv.w;
      }
    }
  }
  const float bias = isv ? VW_b[p] : KW_b[p];
  __half* __restrict__ dst = isv ? val16 : key16;
#pragma unroll
  for (int r = 0; r < 32; ++r)
    dst[(size_t)(r0 + r) * Pc + p] = __float2half(acc[r] + bias);
}

// ---------------- grid barrier ----------------
__device__ __forceinline__ void grid_bar(unsigned* __restrict__ arrive,
                                         unsigned* __restrict__ go, unsigned it) {
  __syncthreads();
  if (threadIdx.x == 0)
    __hip_atomic_store(&arrive[blockIdx.x], it, __ATOMIC_RELEASE, __HIP_MEMORY_SCOPE_AGENT);
  if (blockIdx.x == 0) {
    if (threadIdx.x < 256) {
      while (__hip_atomic_load(&arrive[threadIdx.x], __ATOMIC_ACQUIRE,
                               __HIP_MEMORY_SCOPE_AGENT) < it) {}
    }
    __syncthreads();
    if (threadIdx.x == 0)
      __hip_atomic_store(go, it, __ATOMIC_RELEASE, __HIP_MEMORY_SCOPE_AGENT);
  }
  if (threadIdx.x == 0) {
    while (__hip_atomic_load(go, __ATOMIC_ACQUIRE, __HIP_MEMORY_SCOPE_AGENT) < it) {}
  }
  __syncthreads();
}

// ---------------- LSTM cell phase (runs on all 256 blocks) ----------------
#define CHUNK_COMPUTE(W0_, W1_, W2_, W3_, K0_)                                   \
  {                                                                              \
    _Pragma("unroll") for (int m = 0; m < 4; ++m)                                \
    {                                                                            \
      const int kl = kg * 4 + m * 32;                                            \
      const float4 a0 = *(const float4*)((W0_) + (K0_) + kl);                    \
      const float4 a1 = *(const float4*)((W1_) + (K0_) + kl);                    \
      const float4 a2 = *(const float4*)((W2_) + (K0_) + kl);                    \
      const float4 a3 = *(const float4*)((W3_) + (K0_) + kl);                    \
      _Pragma("unroll") for (int bb = 0; bb < 4; ++bb)                           \
      {                                                                          \
        const float4 xv = *(const float4*)(&xs[bq * 4 + bb][kl]);                \
        acc[0][bb] += a0.x * xv.x + a0.y * xv.y + a0.z * xv.z + a0.w * xv.w;     \
        acc[1][bb] += a1.x * xv.x + a1.y * xv.y + a1.z * xv.z + a1.w * xv.w;     \
        acc[2][bb] += a2.x * xv.x + a2.y * xv.y + a2.z * xv.z + a2.w * xv.w;     \
        acc[3][bb] += a3.x * xv.x + a3.y * xv.y + a3.z * xv.z + a3.w * xv.w;     \
      }                                                                          \
    }                                                                            \
  }

template <int K1>
__device__ __forceinline__ void cell_phase(
    const float* __restrict__ W_ih, const float* __restrict__ W_hh,
    const float* __restrict__ b_ih, const float* __restrict__ b_hh,
    const float* __restrict__ xin,   // (B, K1)
    const float* __restrict__ hold, float* __restrict__ hnew,
    float* __restrict__ cs, float* __restrict__ smem)
{
  const int u0 = (blockIdx.x >> 2) * 8, b0 = (blockIdx.x & 3) * 32;
  const int tid = threadIdx.x;
  const int kg = tid & 7, bq = (tid >> 3) & 7, jq = tid >> 6;
  const int u = u0 + jq;
  float acc[4][4] = {{0.f,0.f,0.f,0.f},{0.f,0.f,0.f,0.f},{0.f,0.f,0.f,0.f},{0.f,0.f,0.f,0.f}};
  float (*xs)[132] = (float (*)[132])smem;

  // ---- segment 1: W_ih * xin ----
  {
    const float* w0 = W_ih + (size_t)(u)        * K1;
    const float* w1 = W_ih + (size_t)(u + 512)  * K1;
    const float* w2 = W_ih + (size_t)(u + 1024) * K1;
    const float* w3 = W_ih + (size_t)(u + 1536) * K1;
#pragma unroll
    for (int c = 0; c < K1 / 128; ++c) {
      const int k0 = c * 128;
      __syncthreads();
#pragma unroll
      for (int i = 0; i < 2; ++i) {
        const int e = i * 512 + tid;
        const int row = e >> 5, c4 = e & 31;
        *(float4*)(&xs[row][c4 * 4]) =
            *(const float4*)(xin + (size_t)(b0 + row) * K1 + k0 + c4 * 4);
      }
      __syncthreads();
      CHUNK_COMPUTE(w0, w1, w2, w3, k0)
    }
  }
  // ---- segment 2: W_hh * h_old ----
  {
    const float* w0 = W_hh + (size_t)(u)        * Hc;
    const float* w1 = W_hh + (size_t)(u + 512)  * Hc;
    const float* w2 = W_hh + (size_t)(u + 1024) * Hc;
    const float* w3 = W_hh + (size_t)(u + 1536) * Hc;
#pragma unroll
    for (int c = 0; c < 4; ++c) {
      const int k0 = c * 128;
      __syncthreads();
#pragma unroll
      for (int i = 0; i < 2; ++i) {
        const int e = i * 512 + tid;
        const int row = e >> 5, c4 = e & 31;
        *(float4*)(&xs[row][c4 * 4]) =
            *(const float4*)(hold + (size_t)(b0 + row) * Hc + k0 + c4 * 4);
      }
      __syncthreads();
      CHUNK_COMPUTE(w0, w1, w2, w3, k0)
    }
  }
  // ---- reduce over kg ----
#pragma unroll
  for (int g = 0; g < 4; ++g) {
#pragma unroll
    for (int bb = 0; bb < 4; ++bb) {
      float v = acc[g][bb];
      v += __shfl_xor(v, 1);
      v += __shfl_xor(v, 2);
      v += __shfl_xor(v, 4);
      acc[g][bb] = v;
    }
  }
  if (kg == 0) {
    const float bi = b_ih[u]        + b_hh[u];
    const float bf = b_ih[u + 512]  + b_hh[u + 512];
    const float bg = b_ih[u + 1024] + b_hh[u + 1024];
    const float bo = b_ih[u + 1536] + b_hh[u + 1536];
#pragma unroll
    for (int bb = 0; bb < 4; ++bb) {
      const int b = b0 + bq * 4 + bb;
      const int idx = b * Hc + u;
      const float ig = sigmoidf_(acc[0][bb] + bi);
      const float fg = sigmoidf_(acc[1][bb] + bf);
      const float gg = tanhf(acc[2][bb] + bg);
      const float og = sigmoidf_(acc[3][bb] + bo);
      const float cn = fg * cs[idx] + ig * gg;
      cs[idx] = cn;
      hnew[idx] = og * tanhf(cn);
    }
  }
}

// ---------------- attention + CDN phase ----------------
__device__ __forceinline__ float wave_max_(float v) {
#pragma unroll
  for (int o = 32; o; o >>= 1) v = fmaxf(v, __shfl_xor(v, o));
  return v;
}
__device__ __forceinline__ float wave_sum_(float v) {
#pragma unroll
  for (int o = 32; o; o >>= 1) v += __shfl_xor(v, o);
  return v;
}

__device__ __forceinline__ void attn_phase(
    const float* __restrict__ h2,      // (B,H) cell2 h_new
    const __half* __restrict__ key16, const __half* __restrict__ val16,
    const int* __restrict__ enc_lens,
    const float* __restrict__ QW_w, const float* __restrict__ QW_b,
    const float* __restrict__ out_w, const float* __restrict__ out_b,
    const float* __restrict__ char_w, const float* __restrict__ char_b,
    const float* __restrict__ emb, const int* __restrict__ y,
    float* __restrict__ xin0,
    float* __restrict__ raw_out, float* __restrict__ attn_out,
    float* __restrict__ smem, const int t)
{
  const int tid = threadIdx.x;
  if (blockIdx.x >= 128) {
    // blocks 128..255: gather next step's embedding into xin0[:, 0:256]
    const int b = blockIdx.x - 128;
    if (tid < 256) {
      const int tok = y[b * Tc + t];   // input token for step t+1
      xin0[b * 384 + tid] = emb[tok * Ec + tid];
    }
    return;
  }
  const int b = blockIdx.x;
  float* h2s  = smem;         // 512
  float* qs   = smem + 512;   // 128
  float* wsm  = smem + 640;   // 600
  float* ctxs = smem + 1240;  // 128
  float* hid  = smem + 1368;  // 256
  float* red  = smem + 1632;  // 8
  float* part = smem + 1648;  // 256

  h2s[tid] = h2[(size_t)b * Hc + tid];
  __syncthreads();
  // q = h2 @ QW^T + b
  if (tid < Pc) {
    const float* wr = QW_w + (size_t)tid * Hc;
    float a = QW_b[tid];
#pragma unroll 8
    for (int k = 0; k < Hc; k += 4) {
      const float4 w = *(const float4*)(wr + k);
      a += w.x * h2s[k] + w.y * h2s[k + 1] + w.z * h2s[k + 2] + w.w * h2s[k + 3];
    }
    qs[tid] = a;
  }
  __syncthreads();
  const int len = enc_lens[b];
  float lmax = -3.0e38f;
  for (int s = tid; s < Sc; s += 512) {
    if (s < len) {
      const __half* kr = key16 + ((size_t)(b * Sc + s)) * Pc;
      float a = 0.f;
#pragma unroll 16
      for (int p = 0; p < Pc; p += 4) {
        const float2 k01 = __half22float2(*(const __half2*)(kr + p));
        const float2 k23 = __half22float2(*(const __half2*)(kr + p + 2));
        a += k01.x * qs[p] + k01.y * qs[p + 1] + k23.x * qs[p + 2] + k23.y * qs[p + 3];
      }
      const float sc = a * 0.08838834764831845f;  // 1/sqrt(128)
      wsm[s] = sc;
      lmax = fmaxf(lmax, sc);
    }
  }
  float wm = wave_max_(lmax);
  if ((tid & 63) == 0) red[tid >> 6] = wm;
  __syncthreads();
  float mx = red[0];
#pragma unroll
  for (int w = 1; w < 8; ++w) mx = fmaxf(mx, red[w]);
  __syncthreads();
  float lsum = 0.f;
  for (int s = tid; s < Sc; s += 512)
    if (s < len) { const float e = expf(wsm[s] - mx); wsm[s] = e; lsum += e; }
  float ws_ = wave_sum_(lsum);
  if ((tid & 63) == 0) red[tid >> 6] = ws_;
  __syncthreads();
  float tot = 0.f;
#pragma unroll
  for (int w = 0; w < 8; ++w) tot += red[w];
  const float inv = 1.f / tot;
  float* ap = attn_out + ((size_t)(b * Tc + t)) * Sc;
  for (int s = tid; s < Sc; s += 512) {
    const float w = (s < len) ? wsm[s] * inv : 0.f;
    wsm[s] = w;
    ap[s] = w;
  }
  __syncthreads();
  // ctx = w @ value, split over 2 s-halves
  if (tid < 256) {
    const int p = tid & 127, hf = tid >> 7;
    const int s_beg = hf * 300;
    const int s_end = (len < (hf + 1) * 300) ? ((len > s_beg) ? len : s_beg) : (hf + 1) * 300;
    const __half* vp = val16 + ((size_t)b * Sc) * Pc + p;
    float a = 0.f;
#pragma unroll 4
    for (int s = s_beg; s < s_end; ++s) a += wsm[s] * __half2float(vp[(size_t)s * Pc]);
    part[hf * 128 + p] = a;
  }
  __syncthreads();
  if (tid < Pc) {
    const float a = part[tid] + part[128 + tid];
    ctxs[tid] = a;
    xin0[b * 384 + 256 + tid] = a;   // ctx part of next step's cell0 input
  }
  __syncthreads();
  // hidden = gelu([h2|ctx] @ out_w^T + out_b)
  if (tid < Ec) {
    const float* wr = out_w + (size_t)tid * (Hc + Pc);
    float a = out_b[tid];
#pragma unroll 8
    for (int k = 0; k < Hc; k += 4) {
      const float4 w = *(const float4*)(wr + k);
      a += w.x * h2s[k] + w.y * h2s[k + 1] + w.z * h2s[k + 2] + w.w * h2s[k + 3];
    }
#pragma unroll 8
    for (int k = 0; k < Pc; k += 4) {
      const float4 w = *(const float4*)(wr + Hc + k);
      a += w.x * ctxs[k] + w.y * ctxs[k + 1] + w.z * ctxs[k + 2] + w.w * ctxs[k + 3];
    }
    hid[tid] = 0.5f * a * (1.f + erff(a * 0.70710678118654752440f));
  }
  __syncthreads();
  if (tid < Vc) {
    const float* wr = char_w + (size_t)tid * Ec;
    float a = char_b[tid];
#pragma unroll 8
    for (int k = 0; k < Ec; k += 4) {
      const float4 w = *(const float4*)(wr + k);
      a += w.x * hid[k] + w.y * hid[k + 1] + w.z * hid[k + 2] + w.w * hid[k + 3];
    }
    raw_out[((size_t)(b * Tc + t)) * Vc + tid] = a;
  }
}

// ---------------- persistent kernel ----------------
struct PParams {
  const float *W_ih0, *W_hh0, *b_ih0, *b_hh0;
  const float *W_ih1, *W_hh1, *b_ih1, *b_hh1;
  const float *W_ih2, *W_hh2, *b_ih2, *b_hh2;
  const float *emb; const int *y; const int *enc;
  const float *QW_w, *QW_b, *out_w, *out_b, *char_w, *char_b;
  const __half *key16, *val16;
  float *hbuf, *cst, *xin0;
  unsigned *bar_arrive, *bar_go;
  float *raw, *attn;
};

__global__ __launch_bounds__(512, 2) void persist_kernel(PParams p) {
  __shared__ float smem[32 * 132];
  unsigned it = 0;
  for (int t = 0; t < Tc; ++t) {
    const float* hold = p.hbuf + (size_t)(t & 1) * (3 * BHc);
    float* hnew = p.hbuf + (size_t)((t & 1) ^ 1) * (3 * BHc);
    cell_phase<384>(p.W_ih0, p.W_hh0, p.b_ih0, p.b_hh0, p.xin0,
                    hold, hnew, p.cst, smem);
    grid_bar(p.bar_arrive, p.bar_go, ++it);
    cell_phase<512>(p.W_ih1, p.W_hh1, p.b_ih1, p.b_hh1, hnew,
                    hold + BHc, hnew + BHc, p.cst + BHc, smem);
    grid_bar(p.bar_arrive, p.bar_go, ++it);
    cell_phase<512>(p.W_ih2, p.W_hh2, p.b_ih2, p.b_hh2, hnew + BHc,
                    hold + 2 * BHc, hnew + 2 * BHc, p.cst + 2 * BHc, smem);
    grid_bar(p.bar_arrive, p.bar_go, ++it);
    attn_phase(hnew + 2 * BHc, p.key16, p.val16, p.enc, p.QW_w, p.QW_b,
               p.out_w, p.out_b, p.char_w, p.char_b, p.emb, p.y,
               p.xin0, p.raw, p.attn, smem, t);
    grid_bar(p.bar_arrive, p.bar_go, ++it);
  }
}

extern "C" void kernel_launch(void* const* d_in, const int* in_sizes, int n_in,
                              void* d_out, int out_size, void* d_ws, size_t ws_size,
                              hipStream_t stream) {
  (void)in_sizes; (void)n_in; (void)out_size; (void)ws_size;
  const float* x      = (const float*)d_in[0];
  const int*   y      = (const int*)  d_in[1];
  const int*   enc    = (const int*)  d_in[2];
  const float* h0     = (const float*)d_in[3];
  const float* c0     = (const float*)d_in[4];
  const float* emb    = (const float*)d_in[5];
  const float* W_ih0  = (const float*)d_in[6];
  const float* W_hh0  = (const float*)d_in[7];
  const float* b_ih0  = (const float*)d_in[8];
  const float* b_hh0  = (const float*)d_in[9];
  const float* W_ih1  = (const float*)d_in[10];
  const float* W_hh1  = (const float*)d_in[11];
  const float* b_ih1  = (const float*)d_in[12];
  const float* b_hh1  = (const float*)d_in[13];
  const float* W_ih2  = (const float*)d_in[14];
  const float* W_hh2  = (const float*)d_in[15];
  const float* b_ih2  = (const float*)d_in[16];
  const float* b_hh2  = (const float*)d_in[17];
  const float* KW_w   = (const float*)d_in[18];
  const float* KW_b   = (const float*)d_in[19];
  const float* VW_w   = (const float*)d_in[20];
  const float* VW_b   = (const float*)d_in[21];
  const float* QW_w   = (const float*)d_in[22];
  const float* QW_b   = (const float*)d_in[23];
  const float* out_w  = (const float*)d_in[24];
  const float* out_b  = (const float*)d_in[25];
  const float* char_w = (const float*)d_in[26];
  const float* char_b = (const float*)d_in[27];

  float* out  = (float*)d_out;
  float* raw  = out;                    // (B,T,V)
  float* attn = out + 793600;           // (B,T,S)

  char* ws = (char*)d_ws;
  __half*   key16 = (__half*)(ws);                                  // 19,660,800 B
  __half*   val16 = (__half*)(ws + 19660800);                       // 19,660,800 B
  float*    hbuf  = (float*)(ws + 39321600);                        // 2*3*B*H
  float*    cst   = (float*)(ws + 39321600 + 1572864);              // 3*B*H
  float*    xin0  = (float*)(ws + 39321600 + 1572864 + 786432);     // B*384
  unsigned* bar   = (unsigned*)(ws + 39321600 + 1572864 + 786432 + 196608);  // 257 u32

  init_kernel<<<768, 256, 0, stream>>>(h0, c0, emb, hbuf, cst, xin0, bar);
  kv_kernel<<<2400, 256, 0, stream>>>(x, KW_w, KW_b, VW_w, VW_b, key16, val16);

  PParams p;
  p.W_ih0 = W_ih0; p.W_hh0 = W_hh0; p.b_ih0 = b_ih0; p.b_hh0 = b_hh0;
  p.W_ih1 = W_ih1; p.W_hh1 = W_hh1; p.b_ih1 = b_ih1; p.b_hh1 = b_hh1;
  p.W_ih2 = W_ih2; p.W_hh2 = W_hh2; p.b_ih2 = b_ih2; p.b_hh2 = b_hh2;
  p.emb = emb; p.y = y; p.enc = enc;
  p.QW_w = QW_w; p.QW_b = QW_b; p.out_w = out_w; p.out_b = out_b;
  p.char_w = char_w; p.char_b = char_b;
  p.key16 = key16; p.val16 = val16;
  p.hbuf = hbuf; p.cst = cst; p.xin0 = xin0;
  p.bar_arrive = bar; p.bar_go = bar + 256;
  p.raw = raw; p.attn = attn;

  void* args[] = { &p };
  hipLaunchCooperativeKernel((const void*)persist_kernel, dim3(256), dim3(512),
                             args, 0, stream);
}